// Round 3
// baseline (159.644 us; speedup 1.0000x reference)
//
#include <hip/hip_runtime.h>

#define NB 64
#define NPG 512
#define LIG 128
#define NBLK 1024          // 16 blocks per graph, 32 rows per block; exactly 4 blocks/CU
#define RPB 32             // rows per block
#define THREADS 512        // 8 waves

// sqrt-free radius tests, bit-exact vs the reference's norm<=cutoff:
// __fsqrt_rn(s) <= 10.0f  <=>  s <= 100 + 2^-17  (0x42C80001)
// __fsqrt_rn(s) <= 8.0f   <=>  s <= 64  + 2^-17  (0x42800001)
__device__ __forceinline__ float dist2(float dx, float dy, float dz) {
    return __fadd_rn(__fadd_rn(__fmul_rn(dx, dx), __fmul_rn(dy, dy)), __fmul_rn(dz, dz));
}
#define T10 __uint_as_float(0x42C80001u)
#define T8  __uint_as_float(0x42800001u)

#define F21 0x1FFFFFull

// unpack a published (cc<<21|ci) word into the packed scan triple
// (cc<<42 | ci<<21 | red), red = ci iff the source block is a ligand block
// (h = j < 4, valid because each lane scans blocks lane*16 + j).
__device__ __forceinline__ unsigned long long pk_triple(unsigned long long v, int j) {
    unsigned long long ci = v & F21;
    unsigned long long cc = (v >> 21) & F21;
    unsigned long long red = (j < 4) ? ci : 0ull;
    return (cc << 42) | (ci << 21) | red;
}

// Single fused kernel, release-counter grid barrier (graph-capture safe):
//  - lane0 publishes pk[b] (relaxed) then fetch_add(cnt,1,release)
//  - wave0 spins on ONE broadcast acquire load of cnt until it reads 1024
//    (release-RMW chain + acquire => all pk stores visible), then reads its
//    16 partials in PARALLEL (one round-trip, no per-word guard chain).
// Deadlock-safe: grid is exactly co-resident -- 1024 blocks = 4/CU x 256 CU,
// guaranteed by __launch_bounds__(512,8) (VGPR<=64) and 8.7 KB LDS/block.
__global__ __launch_bounds__(THREADS, 8) void fused_kernel(const float* __restrict__ X,
                                                           unsigned long long* __restrict__ pk,
                                                           unsigned* __restrict__ cnt,
                                                           int* __restrict__ out) {
    __shared__ float s[NPG * 3];                   // 6 KB coords
    __shared__ unsigned long long smask[RPB * 8];  // 2 KB masks (persist to emit)
    __shared__ int rc[RPB], ri[RPB];               // per-row counts
    __shared__ int sc[RPB], si[RPB];               // global exclusive bases
    __shared__ unsigned long long sblkb, stot;
    __shared__ int sint;

    const int b = blockIdx.x;
    const int g = b >> 4;
    const int h = b & 15;                          // 16 row-groups of 32
    const int t = threadIdx.x;
    const int lane = t & 63;
    const int w = t >> 6;

    // ---------------- phase 1: count ----------------
    if (t < 384) ((float4*)s)[t] = ((const float4*)X)[g * 384 + t];
    if (t < RPB * 8) smask[t] = 0ull;
    __syncthreads();

    float cx[8], cy[8], cz[8];
#pragma unroll
    for (int k = 0; k < 8; ++k) {
        const int c = k * 64 + lane;
        cx[k] = s[3 * c]; cy[k] = s[3 * c + 1]; cz[k] = s[3 * c + 2];
    }

#pragma unroll
    for (int j = 0; j < 4; ++j) {
        const int lr = w * 4 + j;
        const int r = h * 32 + lr;
        const float px = s[3 * r], py = s[3 * r + 1], pz = s[3 * r + 2];
        int cc = 0, ci = 0;
        if (h < 4) {          // ligand rows
            if (r != 0) {
                unsigned long long mm[6];
#pragma unroll
                for (int k = 2; k < 8; ++k) {
                    unsigned long long m =
                        __ballot(dist2(px - cx[k], py - cy[k], pz - cz[k]) <= T10);
                    if (k == 2) m &= ~1ull;        // c=128 is global
                    mm[k - 2] = m;
                    ci += __popcll(m);
                }
                if (lane == 0) {                   // single exec toggle per row
#pragma unroll
                    for (int k = 0; k < 6; ++k) smask[lr * 8 + 2 + k] = mm[k];
                }
            }
        } else if (r != LIG) {  // protein rows
            unsigned long long mm[8];
#pragma unroll
            for (int k = 0; k < 2; ++k) {
                unsigned long long m =
                    __ballot(dist2(px - cx[k], py - cy[k], pz - cz[k]) <= T10);
                if (k == 0) m &= ~1ull;            // c=0 is global
                mm[k] = m;
                ci += __popcll(m);
            }
            const int kr = r >> 6;
            const unsigned long long selfbit = 1ull << (r & 63);
#pragma unroll
            for (int k = 2; k < 8; ++k) {
                unsigned long long m =
                    __ballot(dist2(px - cx[k], py - cy[k], pz - cz[k]) <= T8);
                if (k == 2) m &= ~1ull;            // c=128 is global
                if (k == kr) m &= ~selfbit;        // self edge
                mm[k] = m;
                cc += __popcll(m);
            }
            if (lane == 0) {
#pragma unroll
                for (int k = 0; k < 8; ++k) smask[lr * 8 + k] = mm[k];
            }
        }
        if (lane == 0) { rc[lr] = cc; ri[lr] = ci; }
    }
    __syncthreads();

    // ---------------- phase 2: publish + barrier + scan (wave 0) ----------------
    if (w == 0) {
        // reduce the 32 row counts -> block partials
        int c = (lane < RPB) ? rc[lane] : 0;
        int ii = (lane < RPB) ? ri[lane] : 0;
#pragma unroll
        for (int off = 32; off >= 1; off >>= 1) {
            c += __shfl_down(c, off, 64);
            ii += __shfl_down(ii, off, 64);
        }
        if (lane == 0) {
            const unsigned long long q =
                ((unsigned long long)(unsigned)c << 21) | (unsigned long long)(unsigned)ii;
            __hip_atomic_store(&pk[b], q, __ATOMIC_RELAXED, __HIP_MEMORY_SCOPE_AGENT);
            __hip_atomic_fetch_add(cnt, 1u, __ATOMIC_RELEASE, __HIP_MEMORY_SCOPE_AGENT);
        }
        // broadcast spin: one transaction per wave per poll
        unsigned seen = __hip_atomic_load(cnt, __ATOMIC_ACQUIRE, __HIP_MEMORY_SCOPE_AGENT);
        int guard = 0;
        while (seen != NBLK && ++guard < (1 << 22)) {
            __builtin_amdgcn_s_sleep(2);
            seen = __hip_atomic_load(cnt, __ATOMIC_ACQUIRE, __HIP_MEMORY_SCOPE_AGENT);
        }
        // parallel read of this lane's 16 partials (no guard chain)
        const int base = lane * 16;
        const int idx = b & 15;
        unsigned long long sum = 0, epart = 0;
#pragma unroll
        for (int j = 0; j < 16; ++j) {
            const unsigned long long v =
                __hip_atomic_load(&pk[base + j], __ATOMIC_RELAXED, __HIP_MEMORY_SCOPE_AGENT);
            const unsigned long long tri = pk_triple(v, j);
            sum += tri;
            if (j < idx) epart += tri;             // prefix within the owner chunk
        }
        // packed 64-bit inclusive shuffle scan over 64 lanes
        unsigned long long incl = sum;
#pragma unroll
        for (int off = 1; off < 64; off <<= 1) {
            unsigned long long n = __shfl_up(incl, off, 64);
            if (lane >= off) incl += n;
        }
        if (lane == (b >> 4)) sblkb = (incl - sum) + epart;  // block b excl. prefixes
        if (lane == 63) stot = incl;                         // grand totals (packed)
    }
    __syncthreads();

    const int blkb0 = (int)((sblkb >> 42) & F21);
    const int blkb1 = (int)((sblkb >> 21) & F21);
    const int blkb2 = (int)(sblkb & F21);
    const int Eci = (int)((stot >> 42) & F21);
    const int Ei  = (int)((stot >> 21) & F21);
    const int Er  = (int)(stot & F21);

    if (t < RPB) {  // row counts from LDS (phase 1) -> 32-lane shuffle scan
        const int mc = rc[t];
        const int mi = ri[t];
        int ic = mc, ii = mi;
#pragma unroll
        for (int off = 1; off < 32; off <<= 1) {
            int a0 = __shfl_up(ic, off, 64);
            int a1 = __shfl_up(ii, off, 64);
            if (lane >= off) { ic += a0; ii += a1; }
        }
        sc[t] = blkb0 + ic - mc;                   // global exclusive bases
        si[t] = blkb1 + ii - mi;
        if (t == RPB - 1) sint = ii;               // block's inter total
    }
    __syncthreads();

    const unsigned long long lmask = (1ull << lane) - 1ull;
    const int gn = g * NPG;
    const int Ectx = Eci + NB * 1020 + NB * 2;

    int* ctx_src   = out;
    int* ctx_dst   = out + Ectx;
    int* inter_src = out + 2 * Ectx;
    int* inter_dst = inter_src + Ei;
    int* red_bid   = out + 2 * Ectx + 2 * Ei;
    int* red_off   = red_bid + Er;

    for (int j = 0; j < 4; ++j) {
        const int lr = w * 4 + j;
        const int r = h * 32 + lr;
        const int row = gn + r;

        unsigned long long m[8];
#pragma unroll
        for (int k = 0; k < 8; ++k) m[k] = smask[lr * 8 + k];

        if (h < 4) {
            if (r == 0) {
                // global(seg0) -> ligand cols 1..127 at Eci + g*1020 + (c-1)
                for (int k = 0; k < 2; ++k) {
                    const int c = k * 64 + lane;
                    if (c >= 1 && c < LIG) {
                        const int pos = Eci + g * 1020 + (c - 1);
                        ctx_src[pos] = row; ctx_dst[pos] = gn + c;
                    }
                }
                if (lane == 0) {
                    const int pos = Eci + NB * 1020 + g * 2;  // (0,128)
                    ctx_src[pos] = row; ctx_dst[pos] = gn + LIG;
                }
            } else {  // ligand non-global: inter only (red arrays filled flat below)
                int ib = si[lr];
#pragma unroll
                for (int k = 2; k < 8; ++k) {
                    if (m[k]) {
                        if ((m[k] >> lane) & 1ull) {
                            const int c = k * 64 + lane;
                            const int p = __popcll(m[k] & lmask);
                            inter_src[ib + p] = row; inter_dst[ib + p] = gn + c;
                        }
                        ib += __popcll(m[k]);
                    }
                }
                if (lane == 0) {
                    const int pos = Eci + g * 1020 + (LIG - 1) + (r - 1);  // (r,0)
                    ctx_src[pos] = row; ctx_dst[pos] = gn;
                }
            }
        } else {
            if (r == LIG) {
                // global(seg1) -> protein cols 129..511 at Eci + g*1020 + 254 + (c-129)
                for (int k = 2; k < 8; ++k) {
                    const int c = k * 64 + lane;
                    if (c > LIG) {
                        const int pos = Eci + g * 1020 + 2 * (LIG - 1) + (c - LIG - 1);
                        ctx_src[pos] = row; ctx_dst[pos] = gn + c;
                    }
                }
                if (lane == 0) {
                    const int pos = Eci + NB * 1020 + g * 2 + 1;  // (128,0)
                    ctx_src[pos] = row; ctx_dst[pos] = gn;
                }
            } else {  // protein non-global
                int ib = si[lr];
#pragma unroll
                for (int k = 0; k < 2; ++k) {
                    if (m[k]) {
                        if ((m[k] >> lane) & 1ull) {
                            const int c = k * 64 + lane;
                            const int pos = ib + __popcll(m[k] & lmask);
                            inter_src[pos] = row; inter_dst[pos] = gn + c;
                        }
                        ib += __popcll(m[k]);
                    }
                }
                int cb = sc[lr];
#pragma unroll
                for (int k = 2; k < 8; ++k) {
                    if (m[k]) {
                        if ((m[k] >> lane) & 1ull) {
                            const int c = k * 64 + lane;
                            const int pos = cb + __popcll(m[k] & lmask);
                            ctx_src[pos] = row; ctx_dst[pos] = gn + c;
                        }
                        cb += __popcll(m[k]);
                    }
                }
                if (lane == 0) {
                    const int pos = Eci + g * 1020 + 2 * (LIG - 1) + (NPG - LIG - 1) + (r - LIG - 1);
                    ctx_src[pos] = row; ctx_dst[pos] = gn + LIG;  // (r,128)
                }
            }
        }
    }

    // flat constant fill of the reduced arrays for this block's ligand edges
    if (h < 4) {
        const int rb0 = blkb2;
        const int n = sint;
        for (int i = t; i < n; i += THREADS) {
            red_bid[rb0 + i] = g;
            red_off[rb0 + i] = gn;
        }
    }
}

extern "C" void kernel_launch(void* const* d_in, const int* in_sizes, int n_in,
                              void* d_out, int out_size, void* d_ws, size_t ws_size,
                              hipStream_t stream) {
    (void)in_sizes; (void)n_in; (void)out_size; (void)ws_size;
    const float* X = (const float*)d_in[0];
    unsigned long long* pk = (unsigned long long*)d_ws;   // [1024] packed partials
    unsigned* cnt = (unsigned*)(pk + NBLK);               // barrier counter (own line)
    int* out = (int*)d_out;

    // clear partials + counter each iteration (graph-capture-safe async fill)
    hipMemsetAsync(pk, 0, NBLK * sizeof(unsigned long long) + 64, stream);
    fused_kernel<<<NBLK, THREADS, 0, stream>>>(X, pk, cnt, out);
}

// Round 4
// 136.462 us; speedup vs baseline: 1.1699x; 1.1699x over previous
//
#include <hip/hip_runtime.h>

#define NB 64
#define NPG 512
#define LIG 128
#define NBLK 1024          // 16 blocks per graph, 32 rows per block; exactly 4 blocks/CU
#define RPB 32             // rows per block
#define THREADS 512        // 8 waves

// sqrt-free radius tests, bit-exact vs the reference's norm<=cutoff:
// __fsqrt_rn(s) <= 10.0f  <=>  s <= 100 + 2^-17  (0x42C80001)
// __fsqrt_rn(s) <= 8.0f   <=>  s <= 64  + 2^-17  (0x42800001)
__device__ __forceinline__ float dist2(float dx, float dy, float dz) {
    return __fadd_rn(__fadd_rn(__fmul_rn(dx, dx), __fmul_rn(dy, dy)), __fmul_rn(dz, dz));
}
#define T10 __uint_as_float(0x42C80001u)
#define T8  __uint_as_float(0x42800001u)

#define F21 0x1FFFFFull

// unpack a published (cc<<21|ci) word into the packed scan triple
// (cc<<42 | ci<<21 | red), red = ci iff the source block is a ligand block
// (h = (lane*16+j)&15 = j < 4, since each lane scans blocks lane*16 + j).
__device__ __forceinline__ unsigned long long pk_triple(unsigned long long v, int j) {
    unsigned long long ci = v & F21;
    unsigned long long cc = (v >> 21) & F21;
    unsigned long long red = (j < 4) ? ci : 0ull;
    return (cc << 42) | (ci << 21) | red;
}

// Single fused kernel. Barrier protocol (the round-3 fence-storm fix):
//  - lane0: relaxed store pk[b], then ONE release fetch_add(cnt)
//  - wave0: polls cnt with RELAXED loads (no per-poll cache invalidate),
//    s_sleep(32)-throttled; after seeing 1024, ONE acquire load orders the
//    16 parallel relaxed pk reads that follow.
// Deadlock-safe: grid exactly co-resident (1024 blocks = 4/CU x 256 CU,
// __launch_bounds__(512,8) -> VGPR<=64, 8.9 KB LDS). Bounded guard converts
// any residual pathology into a visible wrong answer, not a hang.
__global__ __launch_bounds__(THREADS, 8) void fused_kernel(const float* __restrict__ X,
                                                           unsigned* __restrict__ cnt,
                                                           unsigned long long* __restrict__ pk,
                                                           int* __restrict__ out) {
    __shared__ float s[NPG * 3];                   // 6 KB coords
    __shared__ unsigned long long smask[RPB * 8];  // 2 KB masks (persist to emit)
    __shared__ int rc[RPB], ri[RPB];               // per-row counts
    __shared__ int sc[RPB], si[RPB];               // global exclusive bases
    __shared__ unsigned long long sblkb, stot;
    __shared__ int sint;

    const int b = blockIdx.x;
    const int g = b >> 4;
    const int h = b & 15;                          // 16 row-groups of 32
    const int t = threadIdx.x;
    const int lane = t & 63;
    const int w = t >> 6;

    // ---------------- phase 1: count ----------------
    if (t < 384) ((float4*)s)[t] = ((const float4*)X)[g * 384 + t];
    if (t < RPB * 8) smask[t] = 0ull;
    __syncthreads();

    float cx[8], cy[8], cz[8];
#pragma unroll
    for (int k = 0; k < 8; ++k) {
        const int c = k * 64 + lane;
        cx[k] = s[3 * c]; cy[k] = s[3 * c + 1]; cz[k] = s[3 * c + 2];
    }

#pragma unroll
    for (int j = 0; j < 4; ++j) {
        const int lr = w * 4 + j;
        const int r = h * 32 + lr;
        const float px = s[3 * r], py = s[3 * r + 1], pz = s[3 * r + 2];
        int cc = 0, ci = 0;
        if (h < 4) {          // ligand rows
            if (r != 0) {
                unsigned long long mm[6];
#pragma unroll
                for (int k = 2; k < 8; ++k) {
                    unsigned long long m =
                        __ballot(dist2(px - cx[k], py - cy[k], pz - cz[k]) <= T10);
                    if (k == 2) m &= ~1ull;        // c=128 is global
                    mm[k - 2] = m;
                    ci += __popcll(m);
                }
                if (lane == 0) {                   // single exec toggle per row
#pragma unroll
                    for (int k = 0; k < 6; ++k) smask[lr * 8 + 2 + k] = mm[k];
                }
            }
        } else if (r != LIG) {  // protein rows
            unsigned long long mm[8];
#pragma unroll
            for (int k = 0; k < 2; ++k) {
                unsigned long long m =
                    __ballot(dist2(px - cx[k], py - cy[k], pz - cz[k]) <= T10);
                if (k == 0) m &= ~1ull;            // c=0 is global
                mm[k] = m;
                ci += __popcll(m);
            }
            const int kr = r >> 6;
            const unsigned long long selfbit = 1ull << (r & 63);
#pragma unroll
            for (int k = 2; k < 8; ++k) {
                unsigned long long m =
                    __ballot(dist2(px - cx[k], py - cy[k], pz - cz[k]) <= T8);
                if (k == 2) m &= ~1ull;            // c=128 is global
                if (k == kr) m &= ~selfbit;        // self edge
                mm[k] = m;
                cc += __popcll(m);
            }
            if (lane == 0) {
#pragma unroll
                for (int k = 0; k < 8; ++k) smask[lr * 8 + k] = mm[k];
            }
        }
        if (lane == 0) { rc[lr] = cc; ri[lr] = ci; }
    }
    __syncthreads();

    // ---------------- phase 2: publish + barrier + scan (wave 0) ----------------
    if (w == 0) {
        // reduce the 32 row counts -> block partials
        int c = (lane < RPB) ? rc[lane] : 0;
        int ii = (lane < RPB) ? ri[lane] : 0;
#pragma unroll
        for (int off = 32; off >= 1; off >>= 1) {
            c += __shfl_down(c, off, 64);
            ii += __shfl_down(ii, off, 64);
        }
        if (lane == 0) {
            const unsigned long long q =
                ((unsigned long long)(unsigned)c << 21) | (unsigned long long)(unsigned)ii;
            __hip_atomic_store(&pk[b], q, __ATOMIC_RELAXED, __HIP_MEMORY_SCOPE_AGENT);
            __hip_atomic_fetch_add(cnt, 1u, __ATOMIC_RELEASE, __HIP_MEMORY_SCOPE_AGENT);
        }
        // RELAXED broadcast poll (no per-poll invalidate), s_sleep-throttled
        unsigned seen = __hip_atomic_load(cnt, __ATOMIC_RELAXED, __HIP_MEMORY_SCOPE_AGENT);
        int guard = 0;
        while (seen != NBLK && ++guard < (1 << 17)) {
            __builtin_amdgcn_s_sleep(32);
            seen = __hip_atomic_load(cnt, __ATOMIC_RELAXED, __HIP_MEMORY_SCOPE_AGENT);
        }
        // ONE acquire to order the pk reads below against all release adds
        (void)__hip_atomic_load(cnt, __ATOMIC_ACQUIRE, __HIP_MEMORY_SCOPE_AGENT);

        // parallel read of this lane's 16 partials
        const int base = lane * 16;
        const int idx = b & 15;
        unsigned long long sum = 0, epart = 0;
#pragma unroll
        for (int j = 0; j < 16; ++j) {
            const unsigned long long v =
                __hip_atomic_load(&pk[base + j], __ATOMIC_RELAXED, __HIP_MEMORY_SCOPE_AGENT);
            const unsigned long long tri = pk_triple(v, j);
            sum += tri;
            if (j < idx) epart += tri;             // prefix within the owner chunk
        }
        // packed 64-bit inclusive shuffle scan over 64 lanes
        unsigned long long incl = sum;
#pragma unroll
        for (int off = 1; off < 64; off <<= 1) {
            unsigned long long n = __shfl_up(incl, off, 64);
            if (lane >= off) incl += n;
        }
        if (lane == (b >> 4)) sblkb = (incl - sum) + epart;  // block b excl. prefixes
        if (lane == 63) stot = incl;                         // grand totals (packed)
    }
    __syncthreads();

    const int blkb0 = (int)((sblkb >> 42) & F21);
    const int blkb1 = (int)((sblkb >> 21) & F21);
    const int blkb2 = (int)(sblkb & F21);
    const int Eci = (int)((stot >> 42) & F21);
    const int Ei  = (int)((stot >> 21) & F21);
    const int Er  = (int)(stot & F21);

    if (t < RPB) {  // row counts from LDS (phase 1) -> 32-lane shuffle scan
        const int mc = rc[t];
        const int mi = ri[t];
        int ic = mc, ii = mi;
#pragma unroll
        for (int off = 1; off < 32; off <<= 1) {
            int a0 = __shfl_up(ic, off, 64);
            int a1 = __shfl_up(ii, off, 64);
            if (lane >= off) { ic += a0; ii += a1; }
        }
        sc[t] = blkb0 + ic - mc;                   // global exclusive bases
        si[t] = blkb1 + ii - mi;
        if (t == RPB - 1) sint = ii;               // block's inter total
    }
    __syncthreads();

    const unsigned long long lmask = (1ull << lane) - 1ull;
    const int gn = g * NPG;
    const int Ectx = Eci + NB * 1020 + NB * 2;

    int* ctx_src   = out;
    int* ctx_dst   = out + Ectx;
    int* inter_src = out + 2 * Ectx;
    int* inter_dst = inter_src + Ei;
    int* red_bid   = out + 2 * Ectx + 2 * Ei;
    int* red_off   = red_bid + Er;

    for (int j = 0; j < 4; ++j) {
        const int lr = w * 4 + j;
        const int r = h * 32 + lr;
        const int row = gn + r;

        unsigned long long m[8];
#pragma unroll
        for (int k = 0; k < 8; ++k) m[k] = smask[lr * 8 + k];

        if (h < 4) {
            if (r == 0) {
                // global(seg0) -> ligand cols 1..127 at Eci + g*1020 + (c-1)
                for (int k = 0; k < 2; ++k) {
                    const int c = k * 64 + lane;
                    if (c >= 1 && c < LIG) {
                        const int pos = Eci + g * 1020 + (c - 1);
                        ctx_src[pos] = row; ctx_dst[pos] = gn + c;
                    }
                }
                if (lane == 0) {
                    const int pos = Eci + NB * 1020 + g * 2;  // (0,128)
                    ctx_src[pos] = row; ctx_dst[pos] = gn + LIG;
                }
            } else {  // ligand non-global: inter only (red arrays filled flat below)
                int ib = si[lr];
#pragma unroll
                for (int k = 2; k < 8; ++k) {
                    if (m[k]) {
                        if ((m[k] >> lane) & 1ull) {
                            const int c = k * 64 + lane;
                            const int p = __popcll(m[k] & lmask);
                            inter_src[ib + p] = row; inter_dst[ib + p] = gn + c;
                        }
                        ib += __popcll(m[k]);
                    }
                }
                if (lane == 0) {
                    const int pos = Eci + g * 1020 + (LIG - 1) + (r - 1);  // (r,0)
                    ctx_src[pos] = row; ctx_dst[pos] = gn;
                }
            }
        } else {
            if (r == LIG) {
                // global(seg1) -> protein cols 129..511 at Eci + g*1020 + 254 + (c-129)
                for (int k = 2; k < 8; ++k) {
                    const int c = k * 64 + lane;
                    if (c > LIG) {
                        const int pos = Eci + g * 1020 + 2 * (LIG - 1) + (c - LIG - 1);
                        ctx_src[pos] = row; ctx_dst[pos] = gn + c;
                    }
                }
                if (lane == 0) {
                    const int pos = Eci + NB * 1020 + g * 2 + 1;  // (128,0)
                    ctx_src[pos] = row; ctx_dst[pos] = gn;
                }
            } else {  // protein non-global
                int ib = si[lr];
#pragma unroll
                for (int k = 0; k < 2; ++k) {
                    if (m[k]) {
                        if ((m[k] >> lane) & 1ull) {
                            const int c = k * 64 + lane;
                            const int pos = ib + __popcll(m[k] & lmask);
                            inter_src[pos] = row; inter_dst[pos] = gn + c;
                        }
                        ib += __popcll(m[k]);
                    }
                }
                int cb = sc[lr];
#pragma unroll
                for (int k = 2; k < 8; ++k) {
                    if (m[k]) {
                        if ((m[k] >> lane) & 1ull) {
                            const int c = k * 64 + lane;
                            const int pos = cb + __popcll(m[k] & lmask);
                            ctx_src[pos] = row; ctx_dst[pos] = gn + c;
                        }
                        cb += __popcll(m[k]);
                    }
                }
                if (lane == 0) {
                    const int pos = Eci + g * 1020 + 2 * (LIG - 1) + (NPG - LIG - 1) + (r - LIG - 1);
                    ctx_src[pos] = row; ctx_dst[pos] = gn + LIG;  // (r,128)
                }
            }
        }
    }

    // flat constant fill of the reduced arrays for this block's ligand edges
    if (h < 4) {
        const int rb0 = blkb2;
        const int n = sint;
        for (int i = t; i < n; i += THREADS) {
            red_bid[rb0 + i] = g;
            red_off[rb0 + i] = gn;
        }
    }
}

extern "C" void kernel_launch(void* const* d_in, const int* in_sizes, int n_in,
                              void* d_out, int out_size, void* d_ws, size_t ws_size,
                              hipStream_t stream) {
    (void)in_sizes; (void)n_in; (void)out_size; (void)ws_size;
    const float* X = (const float*)d_in[0];
    unsigned* cnt = (unsigned*)d_ws;                      // barrier counter, own 64B line
    unsigned long long* pk = (unsigned long long*)((char*)d_ws + 64);  // [1024] partials
    int* out = (int*)d_out;

    // only the counter needs clearing (pk is ordered by cnt); 64B memset node
    hipMemsetAsync(d_ws, 0, 64, stream);
    fused_kernel<<<NBLK, THREADS, 0, stream>>>(X, cnt, pk, out);
}

// Round 5
// 98.865 us; speedup vs baseline: 1.6148x; 1.3803x over previous
//
#include <hip/hip_runtime.h>

#define NB 64
#define NPG 512
#define LIG 128
#define NBLK 1024          // 16 blocks per graph, 32 rows per block; exactly 4 blocks/CU
#define RPB 32             // rows per block
#define THREADS 512        // 8 waves

// sqrt-free radius tests, bit-exact vs the reference's norm<=cutoff:
// __fsqrt_rn(s) <= 10.0f  <=>  s <= 100 + 2^-17  (0x42C80001)
// __fsqrt_rn(s) <= 8.0f   <=>  s <= 64  + 2^-17  (0x42800001)
__device__ __forceinline__ float dist2(float dx, float dy, float dz) {
    return __fadd_rn(__fadd_rn(__fmul_rn(dx, dx), __fmul_rn(dy, dy)), __fmul_rn(dz, dz));
}
#define T10 __uint_as_float(0x42C80001u)
#define T8  __uint_as_float(0x42800001u)

#define F21 0x1FFFFFull

// unpack a published (flag<<63|cc<<21|ci) word into the packed scan triple
// (cc<<42 | ci<<21 | red), red = ci iff the source block is a ligand block
// (h = (lane*16+j)&15 = j < 4, since each lane scans blocks lane*16 + j).
__device__ __forceinline__ unsigned long long pk_triple(unsigned long long v, int j) {
    unsigned long long ci = v & F21;
    unsigned long long cc = (v >> 21) & F21;
    unsigned long long red = (j < 4) ? ci : 0ull;
    return (cc << 42) | (ci << 21) | red;
}

// Single fused kernel. Barrier = DISTRIBUTED FLAGS, no shared counter:
//  - lane0 publishes pk[b] = flag<<63|cc<<21|ci with ONE relaxed agent store
//    (word is self-contained: flag and payload travel in the same 64-bit
//    atom, so no release/acquire pairing needed -- validated in round 2)
//  - wave0 polls its 16 words with INDEPENDENT back-to-back loads (one
//    round-trip per poll round, not a dependent chain), __all across lanes.
// No same-address RMW -> no coherence-point serialization (round-4 lesson).
// Deadlock-safe: grid exactly co-resident (1024 blocks = 4/CU x 256 CU,
// __launch_bounds__(512,8) -> VGPR<=64, 8.9 KB LDS); bounded guard turns any
// pathology into a visible wrong answer, not a hang.
__global__ __launch_bounds__(THREADS, 8) void fused_kernel(const float* __restrict__ X,
                                                           unsigned long long* __restrict__ pk,
                                                           int* __restrict__ out) {
    __shared__ float s[NPG * 3];                   // 6 KB coords
    __shared__ unsigned long long smask[RPB * 8];  // 2 KB masks (persist to emit)
    __shared__ int rc[RPB], ri[RPB];               // per-row counts
    __shared__ int sc[RPB], si[RPB];               // global exclusive bases
    __shared__ unsigned long long sblkb, stot;
    __shared__ int sint;

    const int b = blockIdx.x;
    const int g = b >> 4;
    const int h = b & 15;                          // 16 row-groups of 32
    const int t = threadIdx.x;
    const int lane = t & 63;
    const int w = t >> 6;

    // ---------------- phase 1: count ----------------
    if (t < 384) ((float4*)s)[t] = ((const float4*)X)[g * 384 + t];
    if (t < RPB * 8) smask[t] = 0ull;
    __syncthreads();

    float cx[8], cy[8], cz[8];
#pragma unroll
    for (int k = 0; k < 8; ++k) {
        const int c = k * 64 + lane;
        cx[k] = s[3 * c]; cy[k] = s[3 * c + 1]; cz[k] = s[3 * c + 2];
    }

#pragma unroll
    for (int j = 0; j < 4; ++j) {
        const int lr = w * 4 + j;
        const int r = h * 32 + lr;
        const float px = s[3 * r], py = s[3 * r + 1], pz = s[3 * r + 2];
        int cc = 0, ci = 0;
        if (h < 4) {          // ligand rows
            if (r != 0) {
                unsigned long long mm[6];
#pragma unroll
                for (int k = 2; k < 8; ++k) {
                    unsigned long long m =
                        __ballot(dist2(px - cx[k], py - cy[k], pz - cz[k]) <= T10);
                    if (k == 2) m &= ~1ull;        // c=128 is global
                    mm[k - 2] = m;
                    ci += __popcll(m);
                }
                if (lane == 0) {                   // single exec toggle per row
#pragma unroll
                    for (int k = 0; k < 6; ++k) smask[lr * 8 + 2 + k] = mm[k];
                }
            }
        } else if (r != LIG) {  // protein rows
            unsigned long long mm[8];
#pragma unroll
            for (int k = 0; k < 2; ++k) {
                unsigned long long m =
                    __ballot(dist2(px - cx[k], py - cy[k], pz - cz[k]) <= T10);
                if (k == 0) m &= ~1ull;            // c=0 is global
                mm[k] = m;
                ci += __popcll(m);
            }
            const int kr = r >> 6;
            const unsigned long long selfbit = 1ull << (r & 63);
#pragma unroll
            for (int k = 2; k < 8; ++k) {
                unsigned long long m =
                    __ballot(dist2(px - cx[k], py - cy[k], pz - cz[k]) <= T8);
                if (k == 2) m &= ~1ull;            // c=128 is global
                if (k == kr) m &= ~selfbit;        // self edge
                mm[k] = m;
                cc += __popcll(m);
            }
            if (lane == 0) {
#pragma unroll
                for (int k = 0; k < 8; ++k) smask[lr * 8 + k] = mm[k];
            }
        }
        if (lane == 0) { rc[lr] = cc; ri[lr] = ci; }
    }
    __syncthreads();

    // ---------------- phase 2: publish + flag-poll + scan (wave 0) ----------------
    if (w == 0) {
        // reduce the 32 row counts -> block partials
        int c = (lane < RPB) ? rc[lane] : 0;
        int ii = (lane < RPB) ? ri[lane] : 0;
#pragma unroll
        for (int off = 32; off >= 1; off >>= 1) {
            c += __shfl_down(c, off, 64);
            ii += __shfl_down(ii, off, 64);
        }
        if (lane == 0) {
            const unsigned long long q = (1ull << 63) |
                ((unsigned long long)(unsigned)c << 21) | (unsigned long long)(unsigned)ii;
            __hip_atomic_store(&pk[b], q, __ATOMIC_RELAXED, __HIP_MEMORY_SCOPE_AGENT);
        }
        // parallel flag poll: 16 independent loads per round, AND the flags
        const int base = lane * 16;
        int guard = 0;
        for (;;) {
            unsigned long long conj = ~0ull;
#pragma unroll
            for (int j = 0; j < 16; ++j)
                conj &= __hip_atomic_load(&pk[base + j], __ATOMIC_RELAXED,
                                          __HIP_MEMORY_SCOPE_AGENT);
            if (__all((int)(conj >> 63)) || ++guard >= (1 << 15)) break;
            __builtin_amdgcn_s_sleep(1);
        }
        // re-read the 16 partials (flags now known set; words self-contained)
        const int idx = b & 15;
        unsigned long long sum = 0, epart = 0;
#pragma unroll
        for (int j = 0; j < 16; ++j) {
            const unsigned long long v =
                __hip_atomic_load(&pk[base + j], __ATOMIC_RELAXED, __HIP_MEMORY_SCOPE_AGENT);
            const unsigned long long tri = pk_triple(v, j);
            sum += tri;
            if (j < idx) epart += tri;             // prefix within the owner chunk
        }
        // packed 64-bit inclusive shuffle scan over 64 lanes
        unsigned long long incl = sum;
#pragma unroll
        for (int off = 1; off < 64; off <<= 1) {
            unsigned long long n = __shfl_up(incl, off, 64);
            if (lane >= off) incl += n;
        }
        if (lane == (b >> 4)) sblkb = (incl - sum) + epart;  // block b excl. prefixes
        if (lane == 63) stot = incl;                         // grand totals (packed)
    }
    __syncthreads();

    const int blkb0 = (int)((sblkb >> 42) & F21);
    const int blkb1 = (int)((sblkb >> 21) & F21);
    const int blkb2 = (int)(sblkb & F21);
    const int Eci = (int)((stot >> 42) & F21);
    const int Ei  = (int)((stot >> 21) & F21);
    const int Er  = (int)(stot & F21);

    if (t < RPB) {  // row counts from LDS (phase 1) -> 32-lane shuffle scan
        const int mc = rc[t];
        const int mi = ri[t];
        int ic = mc, ii = mi;
#pragma unroll
        for (int off = 1; off < 32; off <<= 1) {
            int a0 = __shfl_up(ic, off, 64);
            int a1 = __shfl_up(ii, off, 64);
            if (lane >= off) { ic += a0; ii += a1; }
        }
        sc[t] = blkb0 + ic - mc;                   // global exclusive bases
        si[t] = blkb1 + ii - mi;
        if (t == RPB - 1) sint = ii;               // block's inter total
    }
    __syncthreads();

    const unsigned long long lmask = (1ull << lane) - 1ull;
    const int gn = g * NPG;
    const int Ectx = Eci + NB * 1020 + NB * 2;

    int* ctx_src   = out;
    int* ctx_dst   = out + Ectx;
    int* inter_src = out + 2 * Ectx;
    int* inter_dst = inter_src + Ei;
    int* red_bid   = out + 2 * Ectx + 2 * Ei;
    int* red_off   = red_bid + Er;

    for (int j = 0; j < 4; ++j) {
        const int lr = w * 4 + j;
        const int r = h * 32 + lr;
        const int row = gn + r;

        unsigned long long m[8];
#pragma unroll
        for (int k = 0; k < 8; ++k) m[k] = smask[lr * 8 + k];

        if (h < 4) {
            if (r == 0) {
                // global(seg0) -> ligand cols 1..127 at Eci + g*1020 + (c-1)
                for (int k = 0; k < 2; ++k) {
                    const int c = k * 64 + lane;
                    if (c >= 1 && c < LIG) {
                        const int pos = Eci + g * 1020 + (c - 1);
                        ctx_src[pos] = row; ctx_dst[pos] = gn + c;
                    }
                }
                if (lane == 0) {
                    const int pos = Eci + NB * 1020 + g * 2;  // (0,128)
                    ctx_src[pos] = row; ctx_dst[pos] = gn + LIG;
                }
            } else {  // ligand non-global: inter only (red arrays filled flat below)
                int ib = si[lr];
#pragma unroll
                for (int k = 2; k < 8; ++k) {
                    if (m[k]) {
                        if ((m[k] >> lane) & 1ull) {
                            const int c = k * 64 + lane;
                            const int p = __popcll(m[k] & lmask);
                            inter_src[ib + p] = row; inter_dst[ib + p] = gn + c;
                        }
                        ib += __popcll(m[k]);
                    }
                }
                if (lane == 0) {
                    const int pos = Eci + g * 1020 + (LIG - 1) + (r - 1);  // (r,0)
                    ctx_src[pos] = row; ctx_dst[pos] = gn;
                }
            }
        } else {
            if (r == LIG) {
                // global(seg1) -> protein cols 129..511 at Eci + g*1020 + 254 + (c-129)
                for (int k = 2; k < 8; ++k) {
                    const int c = k * 64 + lane;
                    if (c > LIG) {
                        const int pos = Eci + g * 1020 + 2 * (LIG - 1) + (c - LIG - 1);
                        ctx_src[pos] = row; ctx_dst[pos] = gn + c;
                    }
                }
                if (lane == 0) {
                    const int pos = Eci + NB * 1020 + g * 2 + 1;  // (128,0)
                    ctx_src[pos] = row; ctx_dst[pos] = gn;
                }
            } else {  // protein non-global
                int ib = si[lr];
#pragma unroll
                for (int k = 0; k < 2; ++k) {
                    if (m[k]) {
                        if ((m[k] >> lane) & 1ull) {
                            const int c = k * 64 + lane;
                            const int pos = ib + __popcll(m[k] & lmask);
                            inter_src[pos] = row; inter_dst[pos] = gn + c;
                        }
                        ib += __popcll(m[k]);
                    }
                }
                int cb = sc[lr];
#pragma unroll
                for (int k = 2; k < 8; ++k) {
                    if (m[k]) {
                        if ((m[k] >> lane) & 1ull) {
                            const int c = k * 64 + lane;
                            const int pos = cb + __popcll(m[k] & lmask);
                            ctx_src[pos] = row; ctx_dst[pos] = gn + c;
                        }
                        cb += __popcll(m[k]);
                    }
                }
                if (lane == 0) {
                    const int pos = Eci + g * 1020 + 2 * (LIG - 1) + (NPG - LIG - 1) + (r - LIG - 1);
                    ctx_src[pos] = row; ctx_dst[pos] = gn + LIG;  // (r,128)
                }
            }
        }
    }

    // flat constant fill of the reduced arrays for this block's ligand edges
    if (h < 4) {
        const int rb0 = blkb2;
        const int n = sint;
        for (int i = t; i < n; i += THREADS) {
            red_bid[rb0 + i] = g;
            red_off[rb0 + i] = gn;
        }
    }
}

extern "C" void kernel_launch(void* const* d_in, const int* in_sizes, int n_in,
                              void* d_out, int out_size, void* d_ws, size_t ws_size,
                              hipStream_t stream) {
    (void)in_sizes; (void)n_in; (void)out_size; (void)ws_size;
    const float* X = (const float*)d_in[0];
    unsigned long long* pk = (unsigned long long*)d_ws;   // [1024] flagged partials
    int* out = (int*)d_out;

    // clear flags each iteration (stale flags with identical payload would be
    // benign, but iteration-1 garbage would not; 8 KB async fill, capture-safe)
    hipMemsetAsync(pk, 0, NBLK * sizeof(unsigned long long), stream);
    fused_kernel<<<NBLK, THREADS, 0, stream>>>(X, pk, out);
}

// Round 6
// 89.068 us; speedup vs baseline: 1.7924x; 1.1100x over previous
//
#include <hip/hip_runtime.h>

#define NB 64
#define NPG 512
#define LIG 128
#define NBLK 1024          // 16 blocks per graph, 32 rows per block; exactly 4 blocks/CU
#define RPB 32             // rows per block
#define THREADS 512        // 8 waves

// sqrt-free radius tests, bit-exact vs the reference's norm<=cutoff:
// __fsqrt_rn(s) <= 10.0f  <=>  s <= 100 + 2^-17  (0x42C80001)
// __fsqrt_rn(s) <= 8.0f   <=>  s <= 64  + 2^-17  (0x42800001)
__device__ __forceinline__ float dist2(float dx, float dy, float dz) {
    return __fadd_rn(__fadd_rn(__fmul_rn(dx, dx), __fmul_rn(dy, dy)), __fmul_rn(dz, dz));
}
#define T10 __uint_as_float(0x42C80001u)
#define T8  __uint_as_float(0x42800001u)

#define F21  0x1FFFFFull
#define FLG  (1ull << 63)

__device__ __forceinline__ unsigned long long rmw_read(unsigned long long* p) {
    // fetch_add(0): executes at the device coherence point -> never stale
    // (round-5 lesson: relaxed agent LOADS can be served stale from the
    //  non-coherent XCD-local L2; RMWs cannot). Distinct addresses only
    // (round-4 lesson: same-address RMWs serialize ~65ns each).
    return __hip_atomic_fetch_add(p, 0ull, __ATOMIC_RELAXED, __HIP_MEMORY_SCOPE_AGENT);
}

// unpack a published (flag|cc<<21|ci) word into the packed scan triple
// (cc<<42 | ci<<21 | red), red = ci iff the source block is a ligand block
// (h = (lane*16+j)&15 = j < 4, since each lane scans blocks lane*16 + j).
__device__ __forceinline__ unsigned long long pk_triple(unsigned long long v, int j) {
    unsigned long long ci = v & F21;
    unsigned long long cc = (v >> 21) & F21;
    unsigned long long red = (j < 4) ? ci : 0ull;
    return (cc << 42) | (ci << 21) | red;
}

// Single fused kernel; AGGREGATOR barrier (all cross-block reads are RMWs):
//  - every block: lane0 relaxed-stores pk[b] = FLG|cc<<21|ci
//  - block 0 wave 0: polls all 1024 pk flags via fetch_add(0) (16/lane,
//    independent addresses, parallel), packed 64-bit shuffle-scan ->
//    per-block exclusive prefixes + grand totals, writes flagged release
//    words rel[2b] (prefix) and rel[2b+1] (totals)
//  - every other block: wave0 lanes 0..1 poll ONLY rel[2b], rel[2b+1]
//    via fetch_add(0) -- 1024 distinct lines, no contention, stale-proof.
// Deadlock-safe: grid exactly co-resident (1024 blocks = 4/CU x 256 CU,
// __launch_bounds__(512,8) -> VGPR<=64, 8.9 KB LDS); bounded guards turn
// any pathology into a visible wrong answer, not a hang.
__global__ __launch_bounds__(THREADS, 8) void fused_kernel(const float* __restrict__ X,
                                                           unsigned long long* __restrict__ pk,
                                                           unsigned long long* __restrict__ rel,
                                                           int* __restrict__ out) {
    __shared__ float s[NPG * 3];                   // 6 KB coords
    __shared__ unsigned long long smask[RPB * 8];  // 2 KB masks (persist to emit)
    __shared__ int rc[RPB], ri[RPB];               // per-row counts
    __shared__ int sc[RPB], si[RPB];               // global exclusive bases
    __shared__ unsigned long long sblkb, stot;
    __shared__ int sint;

    const int b = blockIdx.x;
    const int g = b >> 4;
    const int h = b & 15;                          // 16 row-groups of 32
    const int t = threadIdx.x;
    const int lane = t & 63;
    const int w = t >> 6;

    // ---------------- phase 1: count ----------------
    if (t < 384) ((float4*)s)[t] = ((const float4*)X)[g * 384 + t];
    if (t < RPB * 8) smask[t] = 0ull;
    __syncthreads();

    float cx[8], cy[8], cz[8];
#pragma unroll
    for (int k = 0; k < 8; ++k) {
        const int c = k * 64 + lane;
        cx[k] = s[3 * c]; cy[k] = s[3 * c + 1]; cz[k] = s[3 * c + 2];
    }

#pragma unroll
    for (int j = 0; j < 4; ++j) {
        const int lr = w * 4 + j;
        const int r = h * 32 + lr;
        const float px = s[3 * r], py = s[3 * r + 1], pz = s[3 * r + 2];
        int cc = 0, ci = 0;
        if (h < 4) {          // ligand rows
            if (r != 0) {
                unsigned long long mm[6];
#pragma unroll
                for (int k = 2; k < 8; ++k) {
                    unsigned long long m =
                        __ballot(dist2(px - cx[k], py - cy[k], pz - cz[k]) <= T10);
                    if (k == 2) m &= ~1ull;        // c=128 is global
                    mm[k - 2] = m;
                    ci += __popcll(m);
                }
                if (lane == 0) {                   // single exec toggle per row
#pragma unroll
                    for (int k = 0; k < 6; ++k) smask[lr * 8 + 2 + k] = mm[k];
                }
            }
        } else if (r != LIG) {  // protein rows
            unsigned long long mm[8];
#pragma unroll
            for (int k = 0; k < 2; ++k) {
                unsigned long long m =
                    __ballot(dist2(px - cx[k], py - cy[k], pz - cz[k]) <= T10);
                if (k == 0) m &= ~1ull;            // c=0 is global
                mm[k] = m;
                ci += __popcll(m);
            }
            const int kr = r >> 6;
            const unsigned long long selfbit = 1ull << (r & 63);
#pragma unroll
            for (int k = 2; k < 8; ++k) {
                unsigned long long m =
                    __ballot(dist2(px - cx[k], py - cy[k], pz - cz[k]) <= T8);
                if (k == 2) m &= ~1ull;            // c=128 is global
                if (k == kr) m &= ~selfbit;        // self edge
                mm[k] = m;
                cc += __popcll(m);
            }
            if (lane == 0) {
#pragma unroll
                for (int k = 0; k < 8; ++k) smask[lr * 8 + k] = mm[k];
            }
        }
        if (lane == 0) { rc[lr] = cc; ri[lr] = ci; }
    }
    __syncthreads();

    // ---------------- phase 2: publish + aggregator barrier ----------------
    if (w == 0) {
        // reduce the 32 row counts -> block partials, publish
        int c = (lane < RPB) ? rc[lane] : 0;
        int ii = (lane < RPB) ? ri[lane] : 0;
#pragma unroll
        for (int off = 32; off >= 1; off >>= 1) {
            c += __shfl_down(c, off, 64);
            ii += __shfl_down(ii, off, 64);
        }
        if (lane == 0) {
            const unsigned long long q = FLG |
                ((unsigned long long)(unsigned)c << 21) | (unsigned long long)(unsigned)ii;
            __hip_atomic_store(&pk[b], q, __ATOMIC_RELAXED, __HIP_MEMORY_SCOPE_AGENT);
        }

        if (b == 0) {
            // ---- aggregator: detect all 1024 publishes (RMW reads) ----
            const int base = lane * 16;
            unsigned long long sum = 0;
            int guard = 0;
            for (;;) {
                unsigned long long conj = ~0ull;
                sum = 0;
#pragma unroll
                for (int j = 0; j < 16; ++j) {
                    const unsigned long long v = rmw_read(&pk[base + j]);
                    conj &= v;
                    sum += pk_triple(v, j);
                }
                if (__all((int)(conj >> 63)) || ++guard >= (1 << 15)) break;
                __builtin_amdgcn_s_sleep(4);
            }
            // packed 64-bit inclusive shuffle scan over lane sums
            unsigned long long incl = sum;
#pragma unroll
            for (int off = 1; off < 64; off <<= 1) {
                unsigned long long n = __shfl_up(incl, off, 64);
                if (lane >= off) incl += n;
            }
            const unsigned long long excl = incl - sum;
            const unsigned long long tots = __shfl(incl, 63);
            // write per-block release words (values now stable; re-RMW-read)
            unsigned long long running = excl;
#pragma unroll
            for (int j = 0; j < 16; ++j) {
                const unsigned long long v = rmw_read(&pk[base + j]);
                __hip_atomic_store(&rel[2 * (base + j)], FLG | running,
                                   __ATOMIC_RELAXED, __HIP_MEMORY_SCOPE_AGENT);
                __hip_atomic_store(&rel[2 * (base + j) + 1], FLG | tots,
                                   __ATOMIC_RELAXED, __HIP_MEMORY_SCOPE_AGENT);
                running += pk_triple(v, j);
            }
            if (lane == 0) { sblkb = 0ull; stot = tots; }  // block 0: zero prefix
        } else {
            // ---- poller: RMW-poll ONLY this block's two release words ----
            unsigned long long vv = 0ull;
            int guard = 0;
            for (;;) {
                if (lane < 2) vv = rmw_read(&rel[2 * b + lane]);
                const int flagged = (lane < 2) ? (int)(vv >> 63) : 1;
                if (__all(flagged) || ++guard >= (1 << 15)) break;
                __builtin_amdgcn_s_sleep(8);
            }
            if (lane == 0) sblkb = vv & ~FLG;
            if (lane == 1) stot  = vv & ~FLG;
        }
    }
    __syncthreads();

    const int blkb0 = (int)((sblkb >> 42) & F21);
    const int blkb1 = (int)((sblkb >> 21) & F21);
    const int blkb2 = (int)(sblkb & F21);
    const int Eci = (int)((stot >> 42) & F21);
    const int Ei  = (int)((stot >> 21) & F21);
    const int Er  = (int)(stot & F21);

    if (t < RPB) {  // row counts from LDS (phase 1) -> 32-lane shuffle scan
        const int mc = rc[t];
        const int mi = ri[t];
        int ic = mc, ii = mi;
#pragma unroll
        for (int off = 1; off < 32; off <<= 1) {
            int a0 = __shfl_up(ic, off, 64);
            int a1 = __shfl_up(ii, off, 64);
            if (lane >= off) { ic += a0; ii += a1; }
        }
        sc[t] = blkb0 + ic - mc;                   // global exclusive bases
        si[t] = blkb1 + ii - mi;
        if (t == RPB - 1) sint = ii;               // block's inter total
    }
    __syncthreads();

    const unsigned long long lmask = (1ull << lane) - 1ull;
    const int gn = g * NPG;
    const int Ectx = Eci + NB * 1020 + NB * 2;

    int* ctx_src   = out;
    int* ctx_dst   = out + Ectx;
    int* inter_src = out + 2 * Ectx;
    int* inter_dst = inter_src + Ei;
    int* red_bid   = out + 2 * Ectx + 2 * Ei;
    int* red_off   = red_bid + Er;

    for (int j = 0; j < 4; ++j) {
        const int lr = w * 4 + j;
        const int r = h * 32 + lr;
        const int row = gn + r;

        unsigned long long m[8];
#pragma unroll
        for (int k = 0; k < 8; ++k) m[k] = smask[lr * 8 + k];

        if (h < 4) {
            if (r == 0) {
                // global(seg0) -> ligand cols 1..127 at Eci + g*1020 + (c-1)
                for (int k = 0; k < 2; ++k) {
                    const int c = k * 64 + lane;
                    if (c >= 1 && c < LIG) {
                        const int pos = Eci + g * 1020 + (c - 1);
                        ctx_src[pos] = row; ctx_dst[pos] = gn + c;
                    }
                }
                if (lane == 0) {
                    const int pos = Eci + NB * 1020 + g * 2;  // (0,128)
                    ctx_src[pos] = row; ctx_dst[pos] = gn + LIG;
                }
            } else {  // ligand non-global: inter only (red arrays filled flat below)
                int ib = si[lr];
#pragma unroll
                for (int k = 2; k < 8; ++k) {
                    if (m[k]) {
                        if ((m[k] >> lane) & 1ull) {
                            const int c = k * 64 + lane;
                            const int p = __popcll(m[k] & lmask);
                            inter_src[ib + p] = row; inter_dst[ib + p] = gn + c;
                        }
                        ib += __popcll(m[k]);
                    }
                }
                if (lane == 0) {
                    const int pos = Eci + g * 1020 + (LIG - 1) + (r - 1);  // (r,0)
                    ctx_src[pos] = row; ctx_dst[pos] = gn;
                }
            }
        } else {
            if (r == LIG) {
                // global(seg1) -> protein cols 129..511 at Eci + g*1020 + 254 + (c-129)
                for (int k = 2; k < 8; ++k) {
                    const int c = k * 64 + lane;
                    if (c > LIG) {
                        const int pos = Eci + g * 1020 + 2 * (LIG - 1) + (c - LIG - 1);
                        ctx_src[pos] = row; ctx_dst[pos] = gn + c;
                    }
                }
                if (lane == 0) {
                    const int pos = Eci + NB * 1020 + g * 2 + 1;  // (128,0)
                    ctx_src[pos] = row; ctx_dst[pos] = gn;
                }
            } else {  // protein non-global
                int ib = si[lr];
#pragma unroll
                for (int k = 0; k < 2; ++k) {
                    if (m[k]) {
                        if ((m[k] >> lane) & 1ull) {
                            const int c = k * 64 + lane;
                            const int pos = ib + __popcll(m[k] & lmask);
                            inter_src[pos] = row; inter_dst[pos] = gn + c;
                        }
                        ib += __popcll(m[k]);
                    }
                }
                int cb = sc[lr];
#pragma unroll
                for (int k = 2; k < 8; ++k) {
                    if (m[k]) {
                        if ((m[k] >> lane) & 1ull) {
                            const int c = k * 64 + lane;
                            const int pos = cb + __popcll(m[k] & lmask);
                            ctx_src[pos] = row; ctx_dst[pos] = gn + c;
                        }
                        cb += __popcll(m[k]);
                    }
                }
                if (lane == 0) {
                    const int pos = Eci + g * 1020 + 2 * (LIG - 1) + (NPG - LIG - 1) + (r - LIG - 1);
                    ctx_src[pos] = row; ctx_dst[pos] = gn + LIG;  // (r,128)
                }
            }
        }
    }

    // flat constant fill of the reduced arrays for this block's ligand edges
    if (h < 4) {
        const int rb0 = blkb2;
        const int n = sint;
        for (int i = t; i < n; i += THREADS) {
            red_bid[rb0 + i] = g;
            red_off[rb0 + i] = gn;
        }
    }
}

extern "C" void kernel_launch(void* const* d_in, const int* in_sizes, int n_in,
                              void* d_out, int out_size, void* d_ws, size_t ws_size,
                              hipStream_t stream) {
    (void)in_sizes; (void)n_in; (void)out_size; (void)ws_size;
    const float* X = (const float*)d_in[0];
    unsigned long long* pk  = (unsigned long long*)d_ws;          // [1024] partials
    unsigned long long* rel = pk + NBLK;                          // [2048] release words
    int* out = (int*)d_out;

    // clear pk + rel flags each iteration (24 KB async fill, capture-safe)
    hipMemsetAsync(d_ws, 0, (NBLK + 2 * NBLK) * sizeof(unsigned long long), stream);
    fused_kernel<<<NBLK, THREADS, 0, stream>>>(X, pk, rel, out);
}